// Round 1
// baseline (207.333 us; speedup 1.0000x reference)
//
#include <hip/hip_runtime.h>

#define KNN_K 3
#define KNN_EPS 1e-8f
#define C_FEAT 128
#define M_QRY 262144

__global__ __launch_bounds__(256) void knn_interp_kernel(
    const float* __restrict__ s_feats,
    const float* __restrict__ q_points,
    const float* __restrict__ s_points,
    const int*   __restrict__ nbr_idx,
    float* __restrict__ out)
{
    const int t  = blockIdx.x * blockDim.x + threadIdx.x;
    const int m  = t >> 5;     // query index (32 lanes per query)
    const int c4 = t & 31;     // which float4 of the 128-channel row
    if (m >= M_QRY) return;

    // Wave-uniform (per 32-lane group) scalar loads — broadcast from L1.
    const int i0 = nbr_idx[m * 3 + 0];
    const int i1 = nbr_idx[m * 3 + 1];
    const int i2 = nbr_idx[m * 3 + 2];

    const float qx = q_points[m * 3 + 0];
    const float qy = q_points[m * 3 + 1];
    const float qz = q_points[m * 3 + 2];

    float dx, dy, dz;
    dx = qx - s_points[i0 * 3 + 0];
    dy = qy - s_points[i0 * 3 + 1];
    dz = qz - s_points[i0 * 3 + 2];
    float w0 = 1.0f / (dx * dx + dy * dy + dz * dz + KNN_EPS);

    dx = qx - s_points[i1 * 3 + 0];
    dy = qy - s_points[i1 * 3 + 1];
    dz = qz - s_points[i1 * 3 + 2];
    float w1 = 1.0f / (dx * dx + dy * dy + dz * dz + KNN_EPS);

    dx = qx - s_points[i2 * 3 + 0];
    dy = qy - s_points[i2 * 3 + 1];
    dz = qz - s_points[i2 * 3 + 2];
    float w2 = 1.0f / (dx * dx + dy * dy + dz * dz + KNN_EPS);

    const float inv_sum = 1.0f / (w0 + w1 + w2);
    w0 *= inv_sum; w1 *= inv_sum; w2 *= inv_sum;

    // Coalesced float4 gathers: 32 lanes cover one 512 B feature row.
    const float4* __restrict__ f0 = (const float4*)(s_feats + (size_t)i0 * C_FEAT);
    const float4* __restrict__ f1 = (const float4*)(s_feats + (size_t)i1 * C_FEAT);
    const float4* __restrict__ f2 = (const float4*)(s_feats + (size_t)i2 * C_FEAT);

    const float4 a = f0[c4];
    const float4 b = f1[c4];
    const float4 c = f2[c4];

    float4 r;
    r.x = w0 * a.x + w1 * b.x + w2 * c.x;
    r.y = w0 * a.y + w1 * b.y + w2 * c.y;
    r.z = w0 * a.z + w1 * b.z + w2 * c.z;
    r.w = w0 * a.w + w1 * b.w + w2 * c.w;

    ((float4*)(out + (size_t)m * C_FEAT))[c4] = r;
}

extern "C" void kernel_launch(void* const* d_in, const int* in_sizes, int n_in,
                              void* d_out, int out_size, void* d_ws, size_t ws_size,
                              hipStream_t stream) {
    const float* s_feats  = (const float*)d_in[0];
    const float* q_points = (const float*)d_in[1];
    const float* s_points = (const float*)d_in[2];
    const int*   nbr_idx  = (const int*)d_in[3];
    float* out = (float*)d_out;

    const int total_threads = M_QRY * 32;       // 32 lanes per query
    const int block = 256;
    const int grid  = (total_threads + block - 1) / block;  // 32768

    knn_interp_kernel<<<grid, block, 0, stream>>>(s_feats, q_points, s_points,
                                                  nbr_idx, out);
}